// Round 4
// baseline (1031.859 us; speedup 1.0000x reference)
//
#include <hip/hip_runtime.h>

#define HH_EPS 1e-8f

constexpr int D       = 2048;           // feature dim
constexpr int K       = 16;             // number of reflections
constexpr int R       = 2;              // rows per batch per wave
constexpr int CH      = D / (64 * 4);   // 8 float4 chunks per lane per row
constexpr int NROWS   = 4 * 4096;       // B * S = 16384
constexpr int TPB     = 1024;           // 16 waves/block
constexpr int BLOCKS  = 256;            // 1 block per CU
constexpr int WAVES   = BLOCKS * (TPB / 64);      // 4096
constexpr int BATCHES = NROWS / (WAVES * R);      // 2 batches of R rows per wave

// ---------------------------------------------------------------------------
// Prologue (1 block, 256 threads): Gram matrix in LDS, then T (larft):
//   T[k][k] = beta_k = 2 / max(G[k][k], EPS)
//   T[i][k] = -beta_k * sum_{j=i}^{k-1} T[i][j] * G[j][k]   (i < k)
// Thread t computes G[t] = v_{t>>4} . v_{t&15} serially (V is 128 KB; the
// 16x reuse rides L1/L2).
// ---------------------------------------------------------------------------
__global__ void __launch_bounds__(256) hh_prep(const float* __restrict__ vecs,
                                               float* __restrict__ T) {
    __shared__ float sG[K * K], sT[K * K];
    const int t = threadIdx.x;
    const int i = t >> 4, j = t & 15;
    const float4* a = (const float4*)(vecs + i * D);
    const float4* b = (const float4*)(vecs + j * D);
    float s = 0.f;
#pragma unroll 8
    for (int c = 0; c < D / 4; ++c) {
        float4 x = a[c], y = b[c];
        s += x.x * y.x + x.y * y.y + x.z * y.z + x.w * y.w;
    }
    sG[t] = s; sT[t] = 0.f;
    __syncthreads();
    for (int k = 0; k < K; ++k) {
        float beta = 2.f / fmaxf(sG[k * K + k], HH_EPS);
        if (t == k) sT[k * K + k] = beta;
        else if (t < k) {
            float acc = 0.f;
            for (int jj = t; jj < k; ++jj) acc += sT[t * K + jj] * sG[jj * K + k];
            sT[t * K + k] = -beta * acc;
        }
        __syncthreads();
    }
    T[t] = sT[t];
}

// ---------------------------------------------------------------------------
// Apply kernel: compact-WY, fully streaming.
// All 16 vectors live in LDS (128 KB, staged once). h is never held in
// registers beyond one float4 chunk per row: the dot pass streams h from
// global (j-outer, k-inner), the update pass re-streams it (L1/L2-warm,
// ~2 us reuse distance) and writes out. Persistent per-thread state is just
// P[2][16] -> ~70 VGPRs, so the R2/R3 scratch-spill failure mode (840 MB of
// scratch writes from long-lived h[R][CH]) is structurally impossible.
// 1024 threads, 129 KB LDS -> 1 block/CU, 4 waves/SIMD.
// ---------------------------------------------------------------------------
__global__ void __launch_bounds__(1024, 4)
hh_apply_stream(const float* __restrict__ h_in, const float* __restrict__ vecs,
                const float* __restrict__ Tmat, float* __restrict__ h_out) {
    __shared__ float4 sv[K * (D / 4)];   // 128 KB: all 16 vectors
    __shared__ float  sT[K * K];         // 1 KB

    const int t    = threadIdx.x;
    const int lane = t & 63;
    const int gw   = blockIdx.x * (TPB / 64) + (t >> 6);   // global wave id

    // Stage all of V: linear LDS dest + contiguous global source (rule #21).
    const float4* v4 = (const float4*)vecs;
#pragma unroll
    for (int i = 0; i < K * (D / 4) / TPB; ++i) {   // 8 rounds of 16 KB
        int idx = t + i * TPB;
        __builtin_amdgcn_global_load_lds(
            (const __attribute__((address_space(1))) unsigned int*)(v4 + idx),
            (__attribute__((address_space(3))) unsigned int*)(sv + idx),
            16, 0, 0);
    }
    if (t < K * K) sT[t] = Tmat[t];
    __syncthreads();   // only barrier in the kernel

    for (int b = 0; b < BATCHES; ++b) {
        const size_t rbase = (size_t)gw * (R * BATCHES) + (size_t)b * R;
        const float4* r0 = (const float4*)h_in + rbase * (D / 4);
        const float4* r1 = r0 + (D / 4);

        // ---- dot pass: P[r][k] = row_r . v_k (per-lane partials) -------
        float P[R][K];
#pragma unroll
        for (int r = 0; r < R; ++r)
#pragma unroll
            for (int k = 0; k < K; ++k) P[r][k] = 0.f;

#pragma unroll
        for (int j = 0; j < CH; ++j) {
            float4 h0 = r0[j * 64 + lane];
            float4 h1 = r1[j * 64 + lane];
#pragma unroll
            for (int k = 0; k < K; ++k) {
                float4 v = sv[k * (D / 4) + j * 64 + lane];
                P[0][k] += h0.x * v.x + h0.y * v.y + h0.z * v.z + h0.w * v.w;
                P[1][k] += h1.x * v.x + h1.y * v.y + h1.z * v.z + h1.w * v.w;
            }
        }

        // ---- one wave-wide butterfly reduce of all 32 partials ---------
#pragma unroll
        for (int off = 32; off >= 1; off >>= 1)
#pragma unroll
            for (int r = 0; r < R; ++r)
#pragma unroll
                for (int k = 0; k < K; ++k)
                    P[r][k] += __shfl_xor(P[r][k], off);

        // ---- w = p . T, in place (upper triangular; descending j safe) -
#pragma unroll
        for (int j = K - 1; j >= 0; --j) {
            float s0 = 0.f, s1 = 0.f;
#pragma unroll
            for (int k = 0; k <= j; ++k) {
                float tk = sT[k * K + j];   // uniform addr -> LDS broadcast
                s0 += P[0][k] * tk;
                s1 += P[1][k] * tk;
            }
            P[0][j] = s0; P[1][j] = s1;
        }

        // ---- update pass: re-stream h (cache-warm), subtract, store ----
        float4* o0 = (float4*)h_out + rbase * (D / 4);
        float4* o1 = o0 + (D / 4);
#pragma unroll
        for (int j = 0; j < CH; ++j) {
            float4 h0 = r0[j * 64 + lane];
            float4 h1 = r1[j * 64 + lane];
#pragma unroll
            for (int k = 0; k < K; ++k) {
                float4 v = sv[k * (D / 4) + j * 64 + lane];
                h0.x -= P[0][k] * v.x; h0.y -= P[0][k] * v.y;
                h0.z -= P[0][k] * v.z; h0.w -= P[0][k] * v.w;
                h1.x -= P[1][k] * v.x; h1.y -= P[1][k] * v.y;
                h1.z -= P[1][k] * v.z; h1.w -= P[1][k] * v.w;
            }
            o0[j * 64 + lane] = h0;
            o1[j * 64 + lane] = h1;
        }
    }
}

extern "C" void kernel_launch(void* const* d_in, const int* in_sizes, int n_in,
                              void* d_out, int out_size, void* d_ws, size_t ws_size,
                              hipStream_t stream) {
    const float* h    = (const float*)d_in[0];   // [4,4096,2048] fp32
    const float* vecs = (const float*)d_in[1];   // [16,2048] fp32
    float* out        = (float*)d_out;           // [4,4096,2048] fp32
    float* Tm         = (float*)d_ws;            // 256 floats

    hh_prep<<<1, 256, 0, stream>>>(vecs, Tm);
    hh_apply_stream<<<BLOCKS, TPB, 0, stream>>>(h, vecs, Tm, out);
}

// Round 5
// 384.965 us; speedup vs baseline: 2.6804x; 2.6804x over previous
//
#include <hip/hip_runtime.h>

#define HH_EPS 1e-8f

constexpr int D       = 2048;           // feature dim
constexpr int K       = 16;             // number of reflections
constexpr int R       = 2;              // rows per batch per wave
constexpr int CH      = D / (64 * 4);   // 8 float4 chunks per lane per row
constexpr int NROWS   = 4 * 4096;       // B * S = 16384
constexpr int TPB     = 512;            // 8 waves/block
constexpr int BLOCKS  = 256;            // 1 block per CU (129 KB LDS forces it)
constexpr int BATCHES = NROWS / (BLOCKS * (TPB / 64) * R);   // 4

// ---------------------------------------------------------------------------
// Kernel 1: Gram matrix G[i][j] = v_i . v_j  (one wave per (i,j) pair).
// Parallel (256 waves) — the merged serial version in R4 cost ~70 us.
// ---------------------------------------------------------------------------
__global__ void __launch_bounds__(64) hh_gram_kernel(const float* __restrict__ vecs,
                                                     float* __restrict__ G) {
    int i = blockIdx.x >> 4, j = blockIdx.x & 15;
    int lane = threadIdx.x;
    const float4* a = (const float4*)(vecs + i * D);
    const float4* b = (const float4*)(vecs + j * D);
    float s = 0.f;
#pragma unroll
    for (int c = 0; c < CH; ++c) {
        float4 x = a[c * 64 + lane], y = b[c * 64 + lane];
        s += x.x * y.x + x.y * y.y + x.z * y.z + x.w * y.w;
    }
#pragma unroll
    for (int off = 32; off >= 1; off >>= 1) s += __shfl_xor(s, off);
    if (lane == 0) G[i * K + j] = s;
}

// ---------------------------------------------------------------------------
// Kernel 2: build T (upper triangular): H0..H15 = I - V T V^T (larft).
//   T[k][k] = beta_k = 2 / max(G[k][k], EPS)
//   T[i][k] = -beta_k * sum_{j=i}^{k-1} T[i][j] * G[j][k]   (i < k)
// 256 threads cover all K*K elements for load/zero/store.
// ---------------------------------------------------------------------------
__global__ void __launch_bounds__(256) hh_buildT_kernel(const float* __restrict__ G,
                                                        float* __restrict__ T) {
    __shared__ float sG[K * K], sT[K * K];
    int t = threadIdx.x;
    sG[t] = G[t]; sT[t] = 0.f;
    __syncthreads();
    for (int k = 0; k < K; ++k) {
        float beta = 2.f / fmaxf(sG[k * K + k], HH_EPS);
        if (t == k) sT[k * K + k] = beta;
        else if (t < k) {
            float s = 0.f;
            for (int j = t; j < k; ++j) s += sT[t * K + j] * sG[j * K + k];
            sT[t * K + k] = -beta * s;
        }
        __syncthreads();
    }
    T[t] = sT[t];
}

// ---------------------------------------------------------------------------
// Apply kernel: compact-WY, fully streaming, REGISTER-PRESSURE-FENCED.
//
// Across R2-R4 the allocator maxed out every VGPR budget (reported count =
// cap/2 each round) and spilled h / v-fragments to scratch, inflating HBM
// traffic ~10x. Two structural fixes:
//   (a) 512-thread blocks + launch_bounds(512,2) -> 256-reg budget (LDS
//       already limits to 1 block/CU, so the big cap costs no occupancy);
//   (b) sched_barrier(0) after every 8-k group -> at most 8 v-fragments
//       (32 VGPRs) in flight; peak liveness ~90 regs. Spill impossible.
// All 16 vectors live in LDS (128 KB, staged once, one barrier). h streams
// chunk-at-a-time with an explicit cur/next prefetch rotation; persistent
// state is only P[2][16].
// ---------------------------------------------------------------------------
__global__ void __launch_bounds__(512, 2)
hh_apply_wy(const float* __restrict__ h_in, const float* __restrict__ vecs,
            const float* __restrict__ Tmat, float* __restrict__ h_out) {
    __shared__ float4 sv[K * (D / 4)];   // 128 KB: all 16 vectors
    __shared__ float  sT[K * K];         // 1 KB

    const int t    = threadIdx.x;
    const int lane = t & 63;
    const int gw   = blockIdx.x * (TPB / 64) + (t >> 6);   // global wave id

    // Stage all of V: linear LDS dest + contiguous global source (rule #21).
    const float4* v4 = (const float4*)vecs;
#pragma unroll
    for (int i = 0; i < K * (D / 4) / TPB; ++i) {   // 16 rounds of 8 KB
        int idx = t + i * TPB;
        __builtin_amdgcn_global_load_lds(
            (const __attribute__((address_space(1))) unsigned int*)(v4 + idx),
            (__attribute__((address_space(3))) unsigned int*)(sv + idx),
            16, 0, 0);
    }
    if (t < K * K) sT[t] = Tmat[t];
    __syncthreads();   // only barrier in the kernel

#pragma unroll 1
    for (int b = 0; b < BATCHES; ++b) {
        const size_t rbase = (size_t)gw * (R * BATCHES) + (size_t)b * R;
        const float4* r0 = (const float4*)h_in + rbase * (D / 4);
        const float4* r1 = r0 + (D / 4);

        // ---- dot pass: P[r][k] = row_r . v_k (per-lane partials) -------
        float P[R][K];
#pragma unroll
        for (int k = 0; k < K; ++k) { P[0][k] = 0.f; P[1][k] = 0.f; }

        float4 c0 = r0[lane], c1 = r1[lane];
#pragma unroll
        for (int j = 0; j < CH; ++j) {
            float4 n0 = c0, n1 = c1;
            if (j < CH - 1) {                      // prefetch next chunk
                n0 = r0[(j + 1) * 64 + lane];
                n1 = r1[(j + 1) * 64 + lane];
            }
#pragma unroll
            for (int kg = 0; kg < K / 8; ++kg) {
#pragma unroll
                for (int kk = 0; kk < 8; ++kk) {
                    const int k = kg * 8 + kk;
                    float4 v = sv[k * (D / 4) + j * 64 + lane];
                    P[0][k] += c0.x * v.x + c0.y * v.y + c0.z * v.z + c0.w * v.w;
                    P[1][k] += c1.x * v.x + c1.y * v.y + c1.z * v.z + c1.w * v.w;
                }
                __builtin_amdgcn_sched_barrier(0);   // bound v-liveness to 8
            }
            c0 = n0; c1 = n1;
        }

        // ---- one wave-wide butterfly reduce of all 32 partials ---------
#pragma unroll
        for (int off = 32; off >= 1; off >>= 1)
#pragma unroll
            for (int k = 0; k < K; ++k) {
                P[0][k] += __shfl_xor(P[0][k], off);
                P[1][k] += __shfl_xor(P[1][k], off);
            }

        // ---- w = p . T, in place (upper triangular; descending j safe) -
#pragma unroll
        for (int j = K - 1; j >= 0; --j) {
            float s0 = 0.f, s1 = 0.f;
#pragma unroll
            for (int k = 0; k <= j; ++k) {
                float tk = sT[k * K + j];   // uniform addr -> LDS broadcast
                s0 += P[0][k] * tk;
                s1 += P[1][k] * tk;
            }
            P[0][j] = s0; P[1][j] = s1;
        }

        // ---- update pass: re-stream h (L2/L3-warm), subtract, store ----
        float4* o0 = (float4*)h_out + rbase * (D / 4);
        float4* o1 = o0 + (D / 4);
        c0 = r0[lane]; c1 = r1[lane];
#pragma unroll
        for (int j = 0; j < CH; ++j) {
            float4 n0 = c0, n1 = c1;
            if (j < CH - 1) {
                n0 = r0[(j + 1) * 64 + lane];
                n1 = r1[(j + 1) * 64 + lane];
            }
#pragma unroll
            for (int kg = 0; kg < K / 8; ++kg) {
#pragma unroll
                for (int kk = 0; kk < 8; ++kk) {
                    const int k = kg * 8 + kk;
                    float4 v = sv[k * (D / 4) + j * 64 + lane];
                    c0.x -= P[0][k] * v.x; c0.y -= P[0][k] * v.y;
                    c0.z -= P[0][k] * v.z; c0.w -= P[0][k] * v.w;
                    c1.x -= P[1][k] * v.x; c1.y -= P[1][k] * v.y;
                    c1.z -= P[1][k] * v.z; c1.w -= P[1][k] * v.w;
                }
                __builtin_amdgcn_sched_barrier(0);
            }
            o0[j * 64 + lane] = c0;
            o1[j * 64 + lane] = c1;
            c0 = n0; c1 = n1;
        }
    }
}

extern "C" void kernel_launch(void* const* d_in, const int* in_sizes, int n_in,
                              void* d_out, int out_size, void* d_ws, size_t ws_size,
                              hipStream_t stream) {
    const float* h    = (const float*)d_in[0];   // [4,4096,2048] fp32
    const float* vecs = (const float*)d_in[1];   // [16,2048] fp32
    float* out        = (float*)d_out;           // [4,4096,2048] fp32

    float* G  = (float*)d_ws;                    // 256 floats
    float* Tm = G + K * K;                       // 256 floats

    hh_gram_kernel<<<K * K, 64, 0, stream>>>(vecs, G);
    hh_buildT_kernel<<<1, 256, 0, stream>>>(G, Tm);
    hh_apply_wy<<<BLOCKS, TPB, 0, stream>>>(h, vecs, Tm, out);
}